// Round 1
// baseline (1626.927 us; speedup 1.0000x reference)
//
#include <hip/hip_runtime.h>
#include <hip/hip_bf16.h>
#include <cstddef>

typedef unsigned short u16;
typedef short bf16x8 __attribute__((ext_vector_type(8)));
typedef unsigned short u16x8 __attribute__((ext_vector_type(8)));
typedef float f32x4 __attribute__((ext_vector_type(4)));

constexpr int CB = 128;    // batch
constexpr int CT = 512;    // time
constexpr int CE = 128;    // embed dim
constexpr int CK = 20;     // tags
constexpr long CM = (long)CB * CT; // 65536 rows (t*CB + b)

// ---- workspace layout (bytes) ----
constexpr size_t OFF_FLAG  = 0;                       // int dtype flag (1=bf16 inputs)
constexpr size_t OFF_WIH0  = 256;                     // bf16 [1024][128]
constexpr size_t OFF_WHH0  = OFF_WIH0 + 262144;       // bf16 [1024][128]
constexpr size_t OFF_WIH1  = OFF_WHH0 + 262144;       // bf16 [1024][256]
constexpr size_t OFF_WHH1  = OFF_WIH1 + 524288;       // bf16 [1024][128]
constexpr size_t OFF_WOUT  = OFF_WHH1 + 262144;       // bf16 [20][256]
constexpr size_t OFF_B0    = OFF_WOUT + 10240;        // f32 [1024]
constexpr size_t OFF_B1    = OFF_B0 + 4096;           // f32 [1024]
constexpr size_t OFF_BOUT  = OFF_B1 + 4096;           // f32 [20]
constexpr size_t OFF_TRANS = OFF_BOUT + 256;          // f32 [400]
constexpr size_t OFF_START = OFF_TRANS + 1792;        // f32 [20]
constexpr size_t OFF_END   = OFF_START + 256;         // f32 [20]
constexpr size_t OFF_PART  = OFF_END + 256;           // f32 [256]: logZ[128], score[128]
constexpr size_t OFF_X0    = 2097152;                 // bf16 [65536][128]
constexpr size_t OFF_H0    = OFF_X0 + 16777216;       // bf16 [65536][256]
constexpr size_t OFF_H1    = OFF_H0 + 33554432;       // bf16 [65536][256]
constexpr size_t OFF_EM    = OFF_H1 + 33554432;       // f32  [65536][20]
constexpr size_t OFF_Z     = OFF_EM + 5242880;        // bf16 [65536][1024] (reused L0/L1)
constexpr size_t WS_NEED   = OFF_Z + 134217728;       // ~225.4 MB

__device__ __forceinline__ float b2f(u16 u) {
    union { unsigned int i; float f; } v; v.i = ((unsigned int)u) << 16; return v.f;
}
__device__ __forceinline__ u16 f2b(float f) {
    union { float f; unsigned int i; } v; v.f = f;
    unsigned int r = v.i + 0x7FFFu + ((v.i >> 16) & 1u);   // RNE
    return (u16)(r >> 16);
}
__device__ __forceinline__ float ldin(const void* p, long i, int bf) {
    return bf ? b2f(((const u16*)p)[i]) : ((const float*)p)[i];
}
__device__ __forceinline__ float sigm(float x) { return 1.0f / (1.0f + __expf(-x)); }
__device__ __forceinline__ float tanh_f(float x) { return 2.0f / (1.0f + __expf(-2.0f * x)) - 1.0f; }

// ---- detect whether float inputs are bf16 or f32, from `trans` (400 uniform(-0.1,0.1)) ----
__global__ void sniff_k(const unsigned char* __restrict__ traw, int* __restrict__ flag) {
    int lane = threadIdx.x;
    int votes = 0;
    // read 200 4-byte words = 800 bytes (safe both ways: bf16->800B total, f32->1600B)
    for (int w = lane; w < 200; w += 64) {
        unsigned char b1 = traw[w * 4 + 1];       // bf16: exponent byte; f32: random mantissa
        unsigned char e = b1 & 0x7F;
        if (e >= 0x20 && e <= 0x3E) votes++;
    }
    #pragma unroll
    for (int off = 32; off; off >>= 1) votes += __shfl_xor(votes, off);
    if (lane == 0) *flag = (votes > 120) ? 1 : 0;
}

// ---- convert all weights into canonical ws copies (bf16 matrices, f32 vectors) ----
__global__ __launch_bounds__(256) void prep_k(
    const void* wih0, const void* whh0, const void* b0,
    const void* wih1, const void* whh1, const void* b1,
    const void* wout, const void* bout, const void* trans,
    const void* start, const void* end, unsigned char* ws)
{
    const int bf = *(const int*)(ws + OFF_FLAG);
    long tid = (long)blockIdx.x * 256 + threadIdx.x;
    u16* wih0b = (u16*)(ws + OFF_WIH0);
    u16* whh0b = (u16*)(ws + OFF_WHH0);
    u16* wih1b = (u16*)(ws + OFF_WIH1);
    u16* whh1b = (u16*)(ws + OFF_WHH1);
    u16* woutb = (u16*)(ws + OFF_WOUT);
    float* b0f   = (float*)(ws + OFF_B0);
    float* b1f   = (float*)(ws + OFF_B1);
    float* boutf = (float*)(ws + OFF_BOUT);
    float* trf   = (float*)(ws + OFF_TRANS);
    float* stf   = (float*)(ws + OFF_START);
    float* enf   = (float*)(ws + OFF_END);

    if (tid < 131072) { wih0b[tid] = f2b(ldin(wih0, tid, bf)); return; } tid -= 131072;
    if (tid < 131072) { whh0b[tid] = f2b(ldin(whh0, tid, bf)); return; } tid -= 131072;
    if (tid < 1024)   { b0f[tid]   = ldin(b0, tid, bf);        return; } tid -= 1024;
    if (tid < 262144) { wih1b[tid] = f2b(ldin(wih1, tid, bf)); return; } tid -= 262144;
    if (tid < 131072) { whh1b[tid] = f2b(ldin(whh1, tid, bf)); return; } tid -= 131072;
    if (tid < 1024)   { b1f[tid]   = ldin(b1, tid, bf);        return; } tid -= 1024;
    if (tid < 5120)   { woutb[tid] = f2b(ldin(wout, tid, bf)); return; } tid -= 5120;
    if (tid < 20)     { boutf[tid] = ldin(bout, tid, bf);      return; } tid -= 20;
    if (tid < 400)    { trf[tid]   = ldin(trans, tid, bf);     return; } tid -= 400;
    if (tid < 20)     { stf[tid]   = ldin(start, tid, bf);     return; } tid -= 20;
    if (tid < 20)     { enf[tid]   = ldin(end, tid, bf);       return; }
}

// ---- embedding gather -> x0 bf16 [m = t*CB+b][128] ----
__global__ __launch_bounds__(256) void gather_k(const void* __restrict__ embed,
                                                const int* __restrict__ sent,
                                                unsigned char* __restrict__ ws)
{
    const int bf = *(const int*)(ws + OFF_FLAG);
    u16* x0 = (u16*)(ws + OFF_X0);
    int tid = blockIdx.x * 256 + threadIdx.x;      // 1,048,576 threads
    int m = tid >> 4, ch = tid & 15;               // 16 chunks of 8 elems per row
    int t = m >> 7, b = m & 127;
    int s = sent[b * CT + t];
    long src = (long)s * CE + ch * 8;
    u16x8 o;
    if (bf) {
        o = *(const u16x8*)((const u16*)embed + src);
    } else {
        const float* ef = (const float*)embed + src;
        f32x4 lo = *(const f32x4*)ef;
        f32x4 hi = *(const f32x4*)(ef + 4);
        o[0]=f2b(lo[0]); o[1]=f2b(lo[1]); o[2]=f2b(lo[2]); o[3]=f2b(lo[3]);
        o[4]=f2b(hi[0]); o[5]=f2b(hi[1]); o[6]=f2b(hi[2]); o[7]=f2b(hi[3]);
    }
    *(u16x8*)(x0 + (long)m * CE + ch * 8) = o;
}

// ---- bf16 MFMA GEMM: C[M,1024] = A[M,KD] @ B[1024,KD]^T, C stored bf16 ----
// block = 256 threads = 4 waves; block covers 16 rows x 1024 cols (wave w: cols w*256..+256)
template<int KD>
__global__ __launch_bounds__(256) void gemm_k(const u16* __restrict__ A,
                                              const u16* __restrict__ Bw,
                                              u16* __restrict__ C)
{
    const int wave = threadIdx.x >> 6, lane = threadIdx.x & 63;
    const int lr = lane & 15, kg = (lane >> 4) * 8;
    const long m0 = (long)blockIdx.x * 16;
    const int n0 = wave * 256;
    const u16* Ap = A + (m0 + lr) * KD + kg;
    const u16* Bp = Bw + (long)(n0 + lr) * KD + kg;
    f32x4 acc[16];
    #pragma unroll
    for (int i = 0; i < 16; ++i) acc[i] = (f32x4){0.f, 0.f, 0.f, 0.f};
    #pragma unroll
    for (int kk = 0; kk < KD; kk += 32) {
        bf16x8 av = *(const bf16x8*)(Ap + kk);
        #pragma unroll
        for (int nt = 0; nt < 16; ++nt) {
            bf16x8 bv = *(const bf16x8*)(Bp + (long)nt * 16 * KD + kk);
            acc[nt] = __builtin_amdgcn_mfma_f32_16x16x32_bf16(av, bv, acc[nt], 0, 0, 0);
        }
    }
    // C/D layout: col = lane&15, row = (lane>>4)*4 + r   [m89/m91-verified]
    const int rr0 = (lane >> 4) * 4;
    #pragma unroll
    for (int nt = 0; nt < 16; ++nt) {
        int col = n0 + nt * 16 + lr;
        #pragma unroll
        for (int r = 0; r < 4; ++r) {
            long row = m0 + rr0 + r;
            C[row * 1024 + col] = f2b(acc[nt][r]);
        }
    }
}

// ---- LSTM scan: one block per (batch b, direction d); 512 threads = one per gate row ----
__global__ __launch_bounds__(512, 2) void scan_k(const u16* __restrict__ Z,
                                                 const u16* __restrict__ Whh,
                                                 const float* __restrict__ bias,
                                                 u16* __restrict__ hout)
{
    const int b = blockIdx.x & 127, d = blockIdx.x >> 7;
    const int g = threadIdx.x;                 // gate row 0..511 (i,f,g,o blocks of 128)
    const u16* wrow = Whh + (long)(d * 512 + g) * 128;
    float w[128];
    #pragma unroll
    for (int k8 = 0; k8 < 16; ++k8) {
        u16x8 u = *(const u16x8*)(wrow + k8 * 8);
        #pragma unroll
        for (int j = 0; j < 8; ++j) w[k8 * 8 + j] = b2f(u[j]);
    }
    const float bg = bias[d * 512 + g];
    __shared__ __align__(16) float hbuf[128];
    __shared__ float zbuf[512];
    float c = 0.f;
    if (g < 128) hbuf[g] = 0.f;
    __syncthreads();

    const long zbase = (long)b * 1024 + (long)d * 512 + g;
    u16 zraw = Z[(long)(d ? CT - 1 : 0) * (CB * 1024) + zbase];
    for (int s = 0; s < CT; ++s) {
        const int t = d ? (CT - 1 - s) : s;
        const float zx = b2f(zraw);
        if (s + 1 < CT) {                       // prefetch next step's xW term
            const int tn = d ? (CT - 2 - s) : (s + 1);
            zraw = Z[(long)tn * (CB * 1024) + zbase];
        }
        float a0 = 0.f, a1 = 0.f, a2 = 0.f, a3 = 0.f;
        #pragma unroll
        for (int k = 0; k < 128; k += 4) {
            f32x4 h4 = *(const f32x4*)(hbuf + k);
            a0 = fmaf(w[k + 0], h4[0], a0);
            a1 = fmaf(w[k + 1], h4[1], a1);
            a2 = fmaf(w[k + 2], h4[2], a2);
            a3 = fmaf(w[k + 3], h4[3], a3);
        }
        const float z = (a0 + a1) + (a2 + a3) + zx + bg;
        // gates i,f,o -> sigmoid; cell gate (256..383) -> tanh. Wave-uniform branch.
        const float act = (g >= 256 && g < 384) ? tanh_f(z) : sigm(z);
        zbuf[g] = act;
        __syncthreads();
        if (g < 128) {
            const float iv = zbuf[g], fv = zbuf[g + 128], gv = zbuf[g + 256], ov = zbuf[g + 384];
            c = fmaf(fv, c, iv * gv);
            const float h = ov * tanh_f(c);
            hbuf[g] = h;
            hout[((long)t * CB + b) * 256 + d * 128 + g] = f2b(h);
        }
        __syncthreads();
    }
}

// ---- emissions: em[m][20] = h1[m] @ Wout^T + bout (f32) ----
__global__ __launch_bounds__(256) void emis_k(const u16* __restrict__ h1,
                                              const u16* __restrict__ woutb,
                                              const float* __restrict__ boutf,
                                              float* __restrict__ em)
{
    __shared__ __align__(16) float wsm[CK * 256];
    for (int i = threadIdx.x; i < CK * 256; i += 256) wsm[i] = b2f(woutb[i]);
    __syncthreads();
    const long m = (long)blockIdx.x * 256 + threadIdx.x;
    const u16* hrow = h1 + m * 256;
    float acc[CK];
    #pragma unroll
    for (int n = 0; n < CK; ++n) acc[n] = boutf[n];
    for (int k8 = 0; k8 < 32; ++k8) {
        u16x8 u = *(const u16x8*)(hrow + k8 * 8);
        float hv[8];
        #pragma unroll
        for (int j = 0; j < 8; ++j) hv[j] = b2f(u[j]);
        #pragma unroll
        for (int n = 0; n < CK; ++n) {
            const f32x4 w0 = *(const f32x4*)&wsm[n * 256 + k8 * 8];
            const f32x4 w1 = *(const f32x4*)&wsm[n * 256 + k8 * 8 + 4];
            acc[n] = fmaf(hv[0], w0[0], acc[n]); acc[n] = fmaf(hv[1], w0[1], acc[n]);
            acc[n] = fmaf(hv[2], w0[2], acc[n]); acc[n] = fmaf(hv[3], w0[3], acc[n]);
            acc[n] = fmaf(hv[4], w1[0], acc[n]); acc[n] = fmaf(hv[5], w1[1], acc[n]);
            acc[n] = fmaf(hv[6], w1[2], acc[n]); acc[n] = fmaf(hv[7], w1[3], acc[n]);
        }
    }
    float* emrow = em + m * CK;
    #pragma unroll
    for (int n = 0; n < CK; ++n) emrow[n] = acc[n];
}

// ---- CRF: blocks 0..127 alpha-scan (logZ), blocks 128..255 numerator (score) ----
__global__ void crf_k(const float* __restrict__ em, const int* __restrict__ tags,
                      const float* __restrict__ trf, const float* __restrict__ stf,
                      const float* __restrict__ enf, float* __restrict__ partial)
{
    const int lane = threadIdx.x;      // 64
    if (blockIdx.x < 128) {
        const int b = blockIdx.x;
        float tcol[CK];
        #pragma unroll
        for (int i = 0; i < CK; ++i) tcol[i] = 0.f;
        if (lane < CK)
            for (int i = 0; i < CK; ++i) tcol[i] = trf[i * CK + lane];
        float alpha = (lane < CK) ? (stf[lane] + em[(long)b * CK + lane]) : -1e30f;
        for (int t = 1; t < CT; ++t) {
            float v[CK]; float mx = -1e30f;
            #pragma unroll
            for (int i = 0; i < CK; ++i) {
                const float ai = __shfl(alpha, i);
                v[i] = ai + tcol[i];
                mx = fmaxf(mx, v[i]);
            }
            float s = 0.f;
            #pragma unroll
            for (int i = 0; i < CK; ++i) s += __expf(v[i] - mx);
            const float emv = (lane < CK) ? em[((long)t * CB + b) * CK + lane] : 0.f;
            const float na = mx + __logf(s) + emv;
            alpha = (lane < CK) ? na : -1e30f;
        }
        float vv = (lane < CK) ? (alpha + enf[lane]) : -1e30f;
        float mx = vv;
        #pragma unroll
        for (int off = 32; off; off >>= 1) mx = fmaxf(mx, __shfl_xor(mx, off));
        float ex = (lane < CK) ? __expf(vv - mx) : 0.f;
        #pragma unroll
        for (int off = 32; off; off >>= 1) ex += __shfl_xor(ex, off);
        if (lane == 0) partial[b] = mx + __logf(ex);
    } else {
        const int b = blockIdx.x - 128;
        float sc = 0.f;
        for (int t = lane; t < CT; t += 64) {
            const int tg = tags[b * CT + t];
            sc += em[((long)t * CB + b) * CK + tg];
            if (t >= 1) sc += trf[tags[b * CT + t - 1] * CK + tg];
        }
        #pragma unroll
        for (int off = 32; off; off >>= 1) sc += __shfl_xor(sc, off);
        if (lane == 0)
            partial[128 + b] = sc + stf[tags[b * CT]] + enf[tags[b * CT + CT - 1]];
    }
}

__global__ void fin_k(const float* __restrict__ partial, void* __restrict__ out,
                      const unsigned char* __restrict__ ws)
{
    const int bf = *(const int*)(ws + OFF_FLAG);
    const int lane = threadIdx.x;  // 64
    float v = (partial[lane] - partial[128 + lane]) + (partial[lane + 64] - partial[192 + lane]);
    #pragma unroll
    for (int off = 32; off; off >>= 1) v += __shfl_xor(v, off);
    if (lane == 0) {
        const float mean = v / 128.f;
        if (bf) ((u16*)out)[0] = f2b(mean);
        else    ((float*)out)[0] = mean;
    }
}

extern "C" void kernel_launch(void* const* d_in, const int* in_sizes, int n_in,
                              void* d_out, int out_size, void* d_ws, size_t ws_size,
                              hipStream_t stream) {
    (void)in_sizes; (void)n_in; (void)out_size;
    if (ws_size < WS_NEED) return;   // fail loudly (output untouched) rather than corrupt
    unsigned char* ws = (unsigned char*)d_ws;

    const void* sent  = d_in[0];
    const void* tags  = d_in[1];
    // d_in[2] = lengths (unused by reference)
    const void* embed = d_in[3];

    u16* x0  = (u16*)(ws + OFF_X0);
    u16* h0  = (u16*)(ws + OFF_H0);
    u16* h1  = (u16*)(ws + OFF_H1);
    u16* Zb  = (u16*)(ws + OFF_Z);
    float* em = (float*)(ws + OFF_EM);
    float* part = (float*)(ws + OFF_PART);

    sniff_k<<<1, 64, 0, stream>>>((const unsigned char*)d_in[12], (int*)(ws + OFF_FLAG));
    prep_k<<<2590, 256, 0, stream>>>(d_in[4], d_in[5], d_in[6], d_in[7], d_in[8],
                                     d_in[9], d_in[10], d_in[11], d_in[12], d_in[13],
                                     d_in[14], ws);
    gather_k<<<4096, 256, 0, stream>>>(embed, (const int*)sent, ws);
    // layer 0
    gemm_k<128><<<4096, 256, 0, stream>>>(x0, (const u16*)(ws + OFF_WIH0), Zb);
    scan_k<<<256, 512, 0, stream>>>(Zb, (const u16*)(ws + OFF_WHH0),
                                    (const float*)(ws + OFF_B0), h0);
    // layer 1
    gemm_k<256><<<4096, 256, 0, stream>>>(h0, (const u16*)(ws + OFF_WIH1), Zb);
    scan_k<<<256, 512, 0, stream>>>(Zb, (const u16*)(ws + OFF_WHH1),
                                    (const float*)(ws + OFF_B1), h1);
    // emissions + CRF
    emis_k<<<256, 256, 0, stream>>>(h1, (const u16*)(ws + OFF_WOUT),
                                    (const float*)(ws + OFF_BOUT), em);
    crf_k<<<256, 64, 0, stream>>>(em, (const int*)tags,
                                  (const float*)(ws + OFF_TRANS),
                                  (const float*)(ws + OFF_START),
                                  (const float*)(ws + OFF_END), part);
    fin_k<<<1, 64, 0, stream>>>(part, d_out, ws);
}